// Round 6
// baseline (142.398 us; speedup 1.0000x reference)
//
#include <hip/hip_runtime.h>
#include <stdint.h>

// SimCLR loss, B=4096, D=512, TAU=0.1.  out[0]=loss, out[1]=acc(%).
//
// Round 6: two kernels only.
//  - Logits are bounded: |cos/tau| <= 10 (+fp8 noise) -> FIXED-max softmax
//    (sum of exp(x-10)). Partials become additive -> atomicAdd per row; the
//    per-tile epilogue is fma+exp+add per value (no online-max serial chains,
//    the round-5 VALU/dependency killer). Row max (accuracy only) via max3 +
//    atomicMax on bias-encoded float bits, pass A only.
//  - finalize runs inside tiles' last block (device atomic counter + fences),
//    killing two kernel launches (~55us of round-5 total was non-tiles).

#define BN 4096
#define DK 512            // K elements = bytes per row in fp8
#define NEG_BIG -1e30f
#define SCL 0.15625f      // 1/(8*8*TAU): undo fp8 pre-scale 8 (both sides), /tau
#define TILE_BYTES (64 * DK)  // 32 KB per 64-col fp8 tile

typedef __attribute__((ext_vector_type(16))) float floatx16;

// ---------------- prep: normalize, fp8-pack (K-permuted), label, zero -----
// Permuted layout: byte position kc2*32 + h*16 + t*8 + j holds original
// k = kc2*32 + t*16 + h*8 + j.  One 16B chunk (kc2,h) = the h-half-wave's
// fragment bytes for kc=2*kc2 and kc=2*kc2+1 (32x32x16 A/B layout:
// lane holds elems k = kc*16 + (lane>>5)*8 + j).
__global__ void __launch_bounds__(256) prep_kernel(
    const float* __restrict__ A, const float* __restrict__ Bv,
    unsigned char* __restrict__ An, unsigned char* __restrict__ Bn,
    float* __restrict__ diag, float* __restrict__ zero_region) {
  {  // zero accLA/accLB/accMA/cnt (harness poisons ws with 0xAA)
    const int idx = blockIdx.x * 256 + threadIdx.x;
    if (idx < 3 * BN + 1) zero_region[idx] = 0.0f;
  }
  const int w = threadIdx.x >> 6, lane = threadIdx.x & 63;
  const int row = blockIdx.x * 4 + w;
  const float4* pa4 = (const float4*)(A + (size_t)row * DK);
  const float4* pb4 = (const float4*)(Bv + (size_t)row * DK);
  float4 a0 = pa4[lane * 2], a1 = pa4[lane * 2 + 1];  // k = lane*8 .. +7
  float4 b0 = pb4[lane * 2], b1 = pb4[lane * 2 + 1];
  float ssa = a0.x * a0.x + a0.y * a0.y + a0.z * a0.z + a0.w * a0.w +
              a1.x * a1.x + a1.y * a1.y + a1.z * a1.z + a1.w * a1.w;
  float ssb = b0.x * b0.x + b0.y * b0.y + b0.z * b0.z + b0.w * b0.w +
              b1.x * b1.x + b1.y * b1.y + b1.z * b1.z + b1.w * b1.w;
  float sab = a0.x * b0.x + a0.y * b0.y + a0.z * b0.z + a0.w * b0.w +
              a1.x * b1.x + a1.y * b1.y + a1.z * b1.z + a1.w * b1.w;
#pragma unroll
  for (int off = 32; off > 0; off >>= 1) {
    ssa += __shfl_xor(ssa, off);
    ssb += __shfl_xor(ssb, off);
    sab += __shfl_xor(sab, off);
  }
  float na = fmaxf(sqrtf(ssa), 1e-12f);
  float nb = fmaxf(sqrtf(ssb), 1e-12f);
  const float s = 8.0f;  // fp8 pre-scale: keeps elems mid-range in e4m3
  float sa = s / na, sb = s / nb;
  const int doff = (lane >> 2) * 32 + (lane & 1) * 16 + ((lane >> 1) & 1) * 8;
  {
    int v0 = __builtin_amdgcn_cvt_pk_fp8_f32(a0.x * sa, a0.y * sa, 0, false);
    v0 = __builtin_amdgcn_cvt_pk_fp8_f32(a0.z * sa, a0.w * sa, v0, true);
    int v1 = __builtin_amdgcn_cvt_pk_fp8_f32(a1.x * sa, a1.y * sa, 0, false);
    v1 = __builtin_amdgcn_cvt_pk_fp8_f32(a1.z * sa, a1.w * sa, v1, true);
    int2 pv; pv.x = v0; pv.y = v1;
    *(int2*)(An + (size_t)row * DK + doff) = pv;
  }
  {
    int v0 = __builtin_amdgcn_cvt_pk_fp8_f32(b0.x * sb, b0.y * sb, 0, false);
    v0 = __builtin_amdgcn_cvt_pk_fp8_f32(b0.z * sb, b0.w * sb, v0, true);
    int v1 = __builtin_amdgcn_cvt_pk_fp8_f32(b1.x * sb, b1.y * sb, 0, false);
    v1 = __builtin_amdgcn_cvt_pk_fp8_f32(b1.z * sb, b1.w * sb, v1, true);
    int2 pv; pv.x = v0; pv.y = v1;
    *(int2*)(Bn + (size_t)row * DK + doff) = pv;
  }
  if (lane == 0) diag[row] = (sab / (na * nb)) * 10.0f;  // exact fp32 /TAU
}

// ---------------- tiles: fp8 MFMA, fixed-max exp-sums, inline finalize ----
// grid = (32 row-blocks, 16 col-splits) = 512 blocks = 2/CU. 4 waves/block,
// wave owns 32 rows. Pass 0 (u<8): a-frags -> full_a sums+max. Pass 1: b-frags
// -> full_b sums. Tiles restaged per pass from the 4MB L2-resident dataset.
__global__ void __launch_bounds__(256, 2) tiles_kernel(
    const unsigned char* __restrict__ An, const unsigned char* __restrict__ Bn,
    const float* __restrict__ diag,
    float* __restrict__ accLA, float* __restrict__ accLB,
    unsigned* __restrict__ accMA, unsigned* __restrict__ cnt,
    float* __restrict__ out) {
  __shared__ __align__(16) unsigned char smem[2 * TILE_BYTES];  // 64 KB

  const int rb = blockIdx.x;     // 0..31 (128-row panel)
  const int split = blockIdx.y;  // 0..15 (8 j-tiles each)
  const int tid = threadIdx.x;
  const int lane = tid & 63, w = tid >> 6;
  const int n5 = lane & 31, h = lane >> 5;
  const int r0 = rb * 128;
  const int myrow = r0 + w * 32 + n5;

  // one view's left fragments (permuted layout -> one long2 = 2 kc frags)
  long af[32];
  auto loadfrags = [&](const unsigned char* base) {
    const unsigned char* p = base + (size_t)myrow * DK + h * 16;
#pragma unroll
    for (int kc2 = 0; kc2 < 16; ++kc2) {
      long2 v = *(const long2*)(p + kc2 * 32);
      af[2 * kc2] = v.x; af[2 * kc2 + 1] = v.y;
    }
  };

  // fixed-max state: l[r] = sum exp(logit-10); mx[r] = max acc (pass A only)
  float l[16], mx[16];
#pragma unroll
  for (int r = 0; r < 16; ++r) { l[r] = 0.f; mx[r] = NEG_BIG; }

  // sum-reduce l (and max-reduce mx) across the 32 n5-lanes, accumulate
  auto flush = [&](float* accL, bool doMax) {
#pragma unroll
    for (int off = 1; off < 32; off <<= 1)
#pragma unroll
      for (int r = 0; r < 16; ++r) {
        l[r] += __shfl_xor(l[r], off);
        if (doMax) mx[r] = fmaxf(mx[r], __shfl_xor(mx[r], off));
      }
    if (n5 == 0) {
#pragma unroll
      for (int r = 0; r < 16; ++r) {
        const int row = r0 + w * 32 + (r & 3) + 8 * (r >> 2) + 4 * h;
        atomicAdd(&accL[row], l[r]);
        if (doMax)  // encode logit+20 (>0) so uint order == float order
          atomicMax(&accMA[row], __float_as_uint(mx[r] * SCL + 20.0f));
      }
    }
#pragma unroll
    for (int r = 0; r < 16; ++r) { l[r] = 0.f; mx[r] = NEG_BIG; }
  };

  // stage a 64-col fp8 tile; one inst = 2 cols (h=0 even col, h=1 odd).
  // XOR swizzle: physical 16B chunk p of col c holds logical chunk p^(c&7).
  auto stage = [&](unsigned char* buf, int jt) {
    const unsigned char* csrc = (jt < 64) ? An : Bn;
    const int cb = (jt & 63) * 64;
#pragma unroll
    for (int ii = 0; ii < 8; ++ii) {  // wave w: colpairs w*8 .. w*8+7
      const int cp = w * 8 + ii;
      const int cl = cp * 2 + h;
      const unsigned char* src =
          csrc + (size_t)(cb + cl) * DK + ((n5 ^ (cl & 7)) * 16);
      __builtin_amdgcn_global_load_lds(
          (const __attribute__((address_space(1))) void*)src,
          (__attribute__((address_space(3))) void*)(buf + cp * 1024),
          16, 0, 0);
    }
  };

  stage(smem, split * 8);
  loadfrags(An);
  __syncthreads();

  for (int u = 0; u < 16; ++u) {
    const int t = u & 7;
    const int jt = split * 8 + t;
    unsigned char* cur = smem + (u & 1) * TILE_BYTES;
    unsigned char* nxt = smem + ((u + 1) & 1) * TILE_BYTES;
    if (u < 15) stage(nxt, split * 8 + ((t + 1) & 7));  // prefetch
    if (u == 8) {  // pass boundary: emit full_a stats, switch to b-frags
      flush(accLA, true);
      loadfrags(Bn);
    }

    floatx16 acc[2];
#pragma unroll
    for (int cs = 0; cs < 2; ++cs)
#pragma unroll
      for (int r = 0; r < 16; ++r) acc[cs][r] = 0.f;

    const unsigned char* bbase = cur + (size_t)n5 * DK;
#pragma unroll
    for (int kc2 = 0; kc2 < 16; ++kc2) {
      const int chunk = ((2 * kc2 + h) ^ (n5 & 7)) * 16;
#pragma unroll
      for (int cs = 0; cs < 2; ++cs) {
        long2 bv = *(const long2*)(bbase + cs * 32 * DK + chunk);
        acc[cs] = __builtin_amdgcn_mfma_f32_32x32x16_fp8_fp8(af[2 * kc2], bv.x, acc[cs], 0, 0, 0);
        acc[cs] = __builtin_amdgcn_mfma_f32_32x32x16_fp8_fp8(af[2 * kc2 + 1], bv.y, acc[cs], 0, 0, 0);
      }
    }

    // epilogue: mask (i,i) of this half (aa/bb masked diag AND ab label —
    // label re-added exactly in finalize), then exp-sum at fixed max 10.
    const bool dtile = (((jt & 63) >> 1) == rb);
    const int colbase = (jt & 63) * 64;
    const bool passA = (u < 8);
#pragma unroll
    for (int r = 0; r < 16; ++r) {
      float v0 = acc[0][r], v1 = acc[1][r];
      if (dtile) {
        const int rowg = r0 + w * 32 + (r & 3) + 8 * (r >> 2) + 4 * h;
        if (rowg == colbase + n5)      v0 = NEG_BIG;
        if (rowg == colbase + 32 + n5) v1 = NEG_BIG;
      }
      if (passA) mx[r] = fmaxf(mx[r], fmaxf(v0, v1));
      l[r] += __expf(v0 * SCL - 10.0f) + __expf(v1 * SCL - 10.0f);
    }
    __syncthreads();  // cur consumed; nxt's DMA drained
  }
  flush(accLB, false);

  // ---- last-block finalize ----
  __syncthreads();  // all flush atomics of this block issued
  unsigned* flag = (unsigned*)smem;
  if (tid == 0) {
    __threadfence();  // release our atomics before the counter bump
    unsigned old = atomicAdd(cnt, 1u);
    *flag = (old == gridDim.x * gridDim.y - 1) ? 1u : 0u;
  }
  __syncthreads();
  if (*flag) {
    __threadfence();  // acquire: see all blocks' accumulates
    float lsum = 0.f, csum = 0.f;
#pragma unroll
    for (int i = 0; i < 16; ++i) {
      const int row = tid + i * 256;
      float La = accLA[row], Lb = accLB[row];
      float Mu = __uint_as_float(accMA[row]) - 20.0f;  // max non-label logit
      float d = diag[row];
      float e = __expf(d - 10.0f);                     // label term
      lsum += (20.0f + logf(La + e) + logf(Lb + e)) - 2.0f * d;
      csum += (d >= Mu) ? 1.f : 0.f;                   // argmax==label
    }
#pragma unroll
    for (int off = 32; off > 0; off >>= 1) {
      lsum += __shfl_xor(lsum, off);
      csum += __shfl_xor(csum, off);
    }
    float* red = (float*)(smem + 64);
    if (lane == 0) { red[w * 2] = lsum; red[w * 2 + 1] = csum; }
    __syncthreads();
    if (tid == 0) {
      float L = red[0] + red[2] + red[4] + red[6];
      float C = red[1] + red[3] + red[5] + red[7];
      out[0] = L * (1.0f / 8192.0f);    // mean over 4096 rows, /2
      out[1] = C * (100.0f / 4096.0f);  // accuracy %
    }
  }
}

extern "C" void kernel_launch(void* const* d_in, const int* in_sizes, int n_in,
                              void* d_out, int out_size, void* d_ws, size_t ws_size,
                              hipStream_t stream) {
  const float* A = (const float*)d_in[0];
  const float* Bv = (const float*)d_in[1];
  unsigned char* An = (unsigned char*)d_ws;                   // 4096x512 fp8
  unsigned char* Bn = An + (size_t)BN * DK;                   // 4096x512 fp8
  float* diag = (float*)(Bn + (size_t)BN * DK);               // 4096 f32
  float* accLA = diag + BN;                                   // 4096 f32
  float* accLB = accLA + BN;                                  // 4096 f32
  unsigned* accMA = (unsigned*)(accLB + BN);                  // 4096 u32
  unsigned* cnt = accMA + BN;                                 // 1 u32
  float* out = (float*)d_out;

  prep_kernel<<<BN / 4, 256, 0, stream>>>(A, Bv, An, Bn, diag, accLA);
  tiles_kernel<<<dim3(32, 16), 256, 0, stream>>>(An, Bn, diag, accLA, accLB,
                                                 accMA, cnt, out);
}